// Round 1
// 611.582 us; speedup vs baseline: 1.0401x; 1.0401x over previous
//
#include <hip/hip_runtime.h>
#include <math.h>

#define D_DIM 1024
#define FF_DIM 4096
#define N_SEQ 257
#define B_SZ 40
#define H_CNT 16
#define HD_DIM 64
#define M_TOK (B_SZ * N_SEQ)   // 10280
#define VT_NP 320               // padded key dim for vT (keys contiguous)

typedef unsigned short u16;
typedef unsigned char u8;
typedef __bf16 bf16x8 __attribute__((ext_vector_type(8)));
typedef float f32x4 __attribute__((ext_vector_type(4)));
typedef int i32x4 __attribute__((ext_vector_type(4)));

__device__ __forceinline__ float b2f(u16 u) {
    union { unsigned int i; float f; } x; x.i = ((unsigned int)u) << 16; return x.f;
}
__device__ __forceinline__ u16 f2b(float f) {
    union { float f; unsigned int i; } x; x.f = f;
    unsigned int r = x.i + 0x7FFFu + ((x.i >> 16) & 1u);  // round-to-nearest-even
    return (u16)(r >> 16);
}
// float -> signed i8 (RNE, clamp +-127), returned as low byte
__device__ __forceinline__ unsigned q8(float f, float s) {
    int q = __float2int_rn(f * s);
    q = q < -127 ? -127 : (q > 127 ? 127 : q);
    return (unsigned)q & 0xFFu;
}

// async global->LDS 16B (dest = wave-uniform base + lane*16; contiguous layout)
__device__ __forceinline__ void g2lds16(const void* g, void* l) {
    __builtin_amdgcn_global_load_lds(
        (const __attribute__((address_space(1))) void*)g,
        (__attribute__((address_space(3))) void*)l,
        16, 0, 0);
}

// ---------------- fused weight conversion + bias concat ----------------
// bf16 dst (contiguous): wqkv[3*nDD] | wo[nDD].  i8 dst: w1i8 (x1024), w2i8 (x1024).
__global__ __launch_bounds__(256)
void cvt_all_kernel(const float* __restrict__ wq, const float* __restrict__ wk,
                    const float* __restrict__ wv, const float* __restrict__ wo,
                    const float* __restrict__ w1, const float* __restrict__ w2,
                    const float* __restrict__ bq, const float* __restrict__ bk,
                    const float* __restrict__ bv,
                    u16* __restrict__ wdst, u8* __restrict__ w1i8,
                    u8* __restrict__ w2i8, float* __restrict__ bqkv) {
    const int nDD = D_DIM * D_DIM, nFD = FF_DIM * D_DIM;
    const int WB8 = (4 * nDD) / 8;       // bf16 8-elem chunks
    const int WF8 = (2 * nFD) / 8;       // i8 8-elem chunks
    const int tid = blockIdx.x * 256 + threadIdx.x;
    if (tid < WB8) {
        const int i = tid * 8;
        const float* src; int s;
        if (i < nDD)          { src = wq; s = i; }
        else if (i < 2 * nDD) { src = wk; s = i - nDD; }
        else if (i < 3 * nDD) { src = wv; s = i - 2 * nDD; }
        else                  { src = wo; s = i - 3 * nDD; }
        float4 a = *(const float4*)(src + s);
        float4 b = *(const float4*)(src + s + 4);
        u16 o[8] = {f2b(a.x), f2b(a.y), f2b(a.z), f2b(a.w),
                    f2b(b.x), f2b(b.y), f2b(b.z), f2b(b.w)};
        *(uint4*)(wdst + i) = *(const uint4*)o;
    } else if (tid < WB8 + WF8) {
        const int j = (tid - WB8) * 8;
        const float* src; u8* dst; int s;
        if (j < nFD) { src = w1; dst = w1i8; s = j; }
        else         { src = w2; dst = w2i8; s = j - nFD; }
        float4 a = *(const float4*)(src + s);
        float4 b = *(const float4*)(src + s + 4);
        const float sc = 1024.f;
        unsigned lo = q8(a.x, sc) | (q8(a.y, sc) << 8) |
                      (q8(a.z, sc) << 16) | (q8(a.w, sc) << 24);
        unsigned hi = q8(b.x, sc) | (q8(b.y, sc) << 8) |
                      (q8(b.z, sc) << 16) | (q8(b.w, sc) << 24);
        uint2 pk = {lo, hi};
        *(uint2*)(dst + s) = pk;
    } else {
        const int j = tid - WB8 - WF8;
        if (j < 3 * D_DIM) {
            bqkv[j] = (j < D_DIM) ? bq[j]
                    : (j < 2 * D_DIM ? bk[j - D_DIM] : bv[j - 2 * D_DIM]);
        }
    }
}

// ---------------- LayerNorm: one block (256 thr) per token row of 1024 ----------------
// I8OUT=false -> bf16 out (u16*), I8OUT=true -> i8 out x16 (u8*)
template <bool I8OUT>
__global__ __launch_bounds__(256)
void ln_kernel(const float* __restrict__ in, const float* __restrict__ w,
               const float* __restrict__ b, void* __restrict__ out) {
    const int row = blockIdx.x;
    const int t = threadIdx.x;
    const size_t base = (size_t)row * D_DIM;
    float x[4];
#pragma unroll
    for (int i = 0; i < 4; ++i) x[i] = in[base + t + i * 256];
    float s  = x[0] + x[1] + x[2] + x[3];
    float ss = x[0]*x[0] + x[1]*x[1] + x[2]*x[2] + x[3]*x[3];
#pragma unroll
    for (int o = 32; o > 0; o >>= 1) {
        s  += __shfl_xor(s, o, 64);
        ss += __shfl_xor(ss, o, 64);
    }
    __shared__ float sh_s[4], sh_ss[4];
    const int wave = t >> 6, lane = t & 63;
    if (lane == 0) { sh_s[wave] = s; sh_ss[wave] = ss; }
    __syncthreads();
    float S  = sh_s[0] + sh_s[1] + sh_s[2] + sh_s[3];
    float SS = sh_ss[0] + sh_ss[1] + sh_ss[2] + sh_ss[3];
    float mean = S * (1.0f / D_DIM);
    float var  = SS * (1.0f / D_DIM) - mean * mean;
    float rstd = rsqrtf(var + 1e-5f);
#pragma unroll
    for (int i = 0; i < 4; ++i) {
        int idx = t + i * 256;
        float y = (x[i] - mean) * rstd * w[idx] + b[idx];
        if (I8OUT) ((u8*)out)[base + idx]  = (u8)q8(y, 16.f);
        else       ((u16*)out)[base + idx] = f2b(y);
    }
}

// ---------------- bf16 GEMM 256x256, 8-phase counted-vmcnt schedule ----------------
// 8 waves (512 thr): wr in {0,1} owns 128 rows, wc in {0..3} owns 64 cols.
// LDS: 8 slots x 16KB, slot = buf*4 + {A:0,1 | B:2,3}[kh]; each slot [256 rows][32 k] bf16
// (64B rows -> full-wave ds_read_b128 is bank-uniform: 8 lanes per 4-bank group).
// Per phase: ds_read frags | vmcnt(6) | stage 1 half-tile (2x global_load_lds dwordx4)
//            | s_barrier | setprio(1) 16x MFMA setprio(0) | s_barrier.
// Stage schedule restages each slot one phase after its 2-phase read window closes;
// every read uses data staged 5-6 phases earlier -> vmcnt(6) (3 half-tiles in flight)
// guarantees landing. Never vmcnt(0) in the main loop (T3+T4).
// MODE 2: out_f32 = extra_f32 + acc + bias (o-proj + residual)
// MODE 5: QKV fused (N=3072): seg0 -> q*0.125, seg1 -> k, seg2 -> vT scatter
#define G256_PHASE(BUF, KH, MH, LOADB, STAGE_STMT)                                   \
  {                                                                                  \
    const u16* sa_ = lds + ((BUF) * 4 + (KH)) * 8192;                                \
    const u16* sb_ = lds + ((BUF) * 4 + 2 + (KH)) * 8192;                            \
    bf16x8 af_[4];                                                                   \
    _Pragma("unroll") for (int mf = 0; mf < 4; ++mf)                                 \
        af_[mf] = *(const bf16x8*)(sa_ + (wr * 128 + (MH) * 64 + mf * 16 + l16) * 32 \
                                       + quad * 8);                                  \
    if (LOADB) {                                                                     \
      _Pragma("unroll") for (int nf = 0; nf < 4; ++nf)                               \
          bf[nf] = *(const bf16x8*)(sb_ + (wc * 64 + nf * 16 + l16) * 32 + quad * 8);\
    }                                                                                \
    asm volatile("s_waitcnt vmcnt(6)" ::: "memory");                                 \
    STAGE_STMT                                                                       \
    asm volatile("" ::: "memory");                                                   \
    __builtin_amdgcn_s_barrier();                                                    \
    asm volatile("" ::: "memory");                                                   \
    __builtin_amdgcn_s_setprio(1);                                                   \
    _Pragma("unroll") for (int mf = 0; mf < 4; ++mf)                                 \
      _Pragma("unroll") for (int nf = 0; nf < 4; ++nf)                               \
          acc[(MH) * 4 + mf][nf] = __builtin_amdgcn_mfma_f32_16x16x32_bf16(          \
              af_[mf], bf[nf], acc[(MH) * 4 + mf][nf], 0, 0, 0);                     \
    __builtin_amdgcn_s_setprio(0);                                                   \
    asm volatile("" ::: "memory");                                                   \
    __builtin_amdgcn_s_barrier();                                                    \
    asm volatile("" ::: "memory");                                                   \
  }

template <int MODE>
__global__ __launch_bounds__(512, 2)
void gemm256_kernel(const u16* __restrict__ A, const u16* __restrict__ Bt,
                    const float* __restrict__ bias, const float* __restrict__ extra,
                    void* __restrict__ out, u16* __restrict__ out2, u16* __restrict__ out3,
                    int M, int N, int K) {
    __shared__ __align__(16) u16 lds[8 * 8192];   // 128 KiB
    const int t = threadIdx.x;
    const int lane = t & 63, wave = t >> 6;
    const int quad = lane >> 4, l16 = lane & 15;
    const int wr = wave >> 2, wc = wave & 3;

    // bijective XCD swizzle (m204: grid not %8==0)
    const int nwg = gridDim.x;
    const int nT = N >> 8;
    const int orig = blockIdx.x;
    const int xcd = orig & 7, loc = orig >> 3;
    const int qq = nwg >> 3, rr = nwg & 7;
    const int wgid = (xcd < rr ? xcd * (qq + 1) : rr * (qq + 1) + (xcd - rr) * qq) + loc;
    const int m0 = (wgid / nT) * 256;
    const int n0 = (wgid % nT) * 256;

    auto stageA = [&](int kt, int kh) {
#pragma unroll
        for (int l = 0; l < 2; ++l) {
            const int c = l * 512 + t;             // 16B chunk: row=c>>2, kcol=(c&3)*8
            int gr = m0 + (c >> 2); if (gr > M - 1) gr = M - 1;
            g2lds16(A + (size_t)gr * K + kt * 64 + kh * 32 + (c & 3) * 8,
                    lds + ((kt & 1) * 4 + kh) * 8192 + c * 8);
        }
    };
    auto stageB = [&](int kt, int kh) {
#pragma unroll
        for (int l = 0; l < 2; ++l) {
            const int c = l * 512 + t;
            g2lds16(Bt + (size_t)(n0 + (c >> 2)) * K + kt * 64 + kh * 32 + (c & 3) * 8,
                    lds + ((kt & 1) * 4 + 2 + kh) * 8192 + c * 8);
        }
    };

    f32x4 acc[8][4];
#pragma unroll
    for (int mi = 0; mi < 8; ++mi)
#pragma unroll
        for (int nf = 0; nf < 4; ++nf) acc[mi][nf] = {0.f, 0.f, 0.f, 0.f};
    bf16x8 bf[4];   // persists across the (mh0, mh1) phase pair

    // prologue: kt0 fully + kt1's kh0 (6 half-tiles); kt1-kh1 staged at iter0 ph1/ph2
    stageA(0, 0); stageB(0, 0); stageA(0, 1); stageB(0, 1); stageA(1, 0); stageB(1, 0);
    asm volatile("s_waitcnt vmcnt(0)" ::: "memory");
    __builtin_amdgcn_s_barrier();
    asm volatile("" ::: "memory");

    const int NIT = K >> 7;                        // 2 K-tiles (BK=64) per iteration
    for (int i = 0; i < NIT; ++i) {
        const int kt0 = 2 * i;
        const bool more = (i < NIT - 1);
        G256_PHASE(0, 0, 0, true,  { stageA(kt0 + 1, 1); })
        G256_PHASE(0, 0, 1, false, { stageB(kt0 + 1, 1); })
        G256_PHASE(0, 1, 0, true,  { if (more) stageA(kt0 + 2, 0); })
        G256_PHASE(0, 1, 1, false, { if (more) stageB(kt0 + 2, 0); })
        G256_PHASE(1, 0, 0, true,  { if (more) stageA(kt0 + 2, 1); })
        G256_PHASE(1, 0, 1, false, { if (more) stageB(kt0 + 2, 1); })
        G256_PHASE(1, 1, 0, true,  { if (more) stageA(kt0 + 3, 0); })
        G256_PHASE(1, 1, 1, false, { if (more) stageB(kt0 + 3, 0); })
    }

    // epilogue: C/D layout col=l16, row=quad*4+i (verified mapping)
#pragma unroll
    for (int mi = 0; mi < 8; ++mi) {
#pragma unroll
        for (int nf = 0; nf < 4; ++nf) {
            const int n = n0 + wc * 64 + nf * 16 + l16;
            const float bvf = bias[n];
#pragma unroll
            for (int i2 = 0; i2 < 4; ++i2) {
                const int m = m0 + wr * 128 + mi * 16 + quad * 4 + i2;
                if (m >= M) continue;
                float v = acc[mi][nf][i2] + bvf;
                if (MODE == 2) {
                    const size_t idx = (size_t)m * N + n;
                    ((float*)out)[idx] = extra[idx] + v;
                } else {  // MODE 5
                    const int seg = n >> 10, nl = n & 1023;
                    if (seg == 0) {
                        ((u16*)out)[(size_t)m * D_DIM + nl] = f2b(v * 0.125f);
                    } else if (seg == 1) {
                        out2[(size_t)m * D_DIM + nl] = f2b(v);
                    } else {
                        const int bb = m / N_SEQ;
                        const int tt = m - bb * N_SEQ;
                        out3[((size_t)bb * D_DIM + nl) * VT_NP + tt] = f2b(v);
                    }
                }
            }
        }
    }
}

// ---------------- i8 GEMM 128x128, BK=128, mfma_i32_16x16x64_i8 ----------------
// A i8 [M,K] (scale sA_inv folded in epilogue), Bt i8 [N,K] (x1024).
// MODE 2: out_f32 = extra_f32 + acc/32768 + bias   (fc2 + residual -> d_out)
// MODE 3: out_i8  = quickgelu(acc/16384 + bias) x32  (fc1 -> h1i8)
template <int MODE>
__global__ __launch_bounds__(256)
void gemm_i8_kernel(const u8* __restrict__ A, const u8* __restrict__ Bt,
                    const float* __restrict__ bias, const float* __restrict__ extra,
                    void* __restrict__ out, int M, int N, int K, int sw) {
    __shared__ __align__(16) u8 sA[128 * 128];   // 16 KB
    __shared__ __align__(16) u8 sB[128 * 128];   // 16 KB
    const int t = threadIdx.x;

    const int nM = gridDim.x, nN = gridDim.y;
    const int lid   = blockIdx.y * nM + blockIdx.x;
    const int csz   = sw * nN;
    const int chunk = lid / csz;
    const int rem   = lid - chunk * csz;
    const int n0 = (rem % nN) * 128;
    const int m0 = (chunk * sw + rem / nN) * 128;

    const int wave = t >> 6, lane = t & 63;
    const int quad = lane >> 4, l16 = lane & 15;
    const int wm = (wave >> 1) * 64, wn = (wave & 1) * 64;

    const u8* gA[4]; const u8* gB[4]; u8* lA[4]; u8* lB[4];
#pragma unroll
    for (int i = 0; i < 4; ++i) {
        const int c = i * 256 + t;
        const int row = c >> 3;
        const int sg = (c & 7) ^ (row & 7);
        int gr = m0 + row; if (gr > M - 1) gr = M - 1;
        gA[i] = A  + (size_t)gr * K + sg * 16;
        gB[i] = Bt + (size_t)(n0 + row) * K + sg * 16;
        lA[i] = sA + c * 16;
        lB[i] = sB + c * 16;
    }

    i32x4 acc[4][4];
#pragma unroll
    for (int mt = 0; mt < 4; ++mt)
#pragma unroll
        for (int nt = 0; nt < 4; ++nt) acc[mt][nt] = {0, 0, 0, 0};

    for (int k0 = 0; k0 < K; k0 += 128) {
        __syncthreads();
#pragma unroll
        for (int i = 0; i < 4; ++i) g2lds16(gA[i] + k0, lA[i]);
#pragma unroll
        for (int i = 0; i < 4; ++i) g2lds16(gB[i] + k0, lB[i]);
        __syncthreads();
#pragma unroll
        for (int j = 0; j < 2; ++j) {
            i32x4 af[4], bfr[4];
#pragma unroll
            for (int mt = 0; mt < 4; ++mt) {
                const int r = wm + mt * 16 + l16;
                af[mt] = *(const i32x4*)(sA + r * 128 + (((j * 4 + quad) ^ (r & 7)) * 16));
            }
#pragma unroll
            for (int nt = 0; nt < 4; ++nt) {
                const int n = wn + nt * 16 + l16;
                bfr[nt] = *(const i32x4*)(sB + n * 128 + (((j * 4 + quad) ^ (n & 7)) * 16));
            }
#pragma unroll
            for (int mt = 0; mt < 4; ++mt)
#pragma unroll
                for (int nt = 0; nt < 4; ++nt)
                    acc[mt][nt] = __builtin_amdgcn_mfma_i32_16x16x64_i8(
                        af[mt], bfr[nt], acc[mt][nt], 0, 0, 0);
        }
    }

    const float sc = (MODE == 2) ? (1.f / 32768.f) : (1.f / 16384.f);
#pragma unroll
    for (int mt = 0; mt < 4; ++mt) {
#pragma unroll
        for (int nt = 0; nt < 4; ++nt) {
            const int n = n0 + wn + nt * 16 + l16;
            const float bvf = bias[n];
#pragma unroll
            for (int i = 0; i < 4; ++i) {
                const int m = m0 + wm + mt * 16 + quad * 4 + i;
                if (m >= M) continue;
                float v = (float)acc[mt][nt][i] * sc + bvf;
                if (MODE == 2) {
                    const size_t idx = (size_t)m * N + n;
                    ((float*)out)[idx] = extra[idx] + v;
                } else {  // MODE 3: quickgelu -> i8 x32
                    float g = v / (1.0f + __expf(-1.702f * v));
                    ((u8*)out)[(size_t)m * N + n] = (u8)q8(g, 32.f);
                }
            }
        }
    }
}

// ---------------- MFMA attention v4 (unchanged) ----------------
#define ATT_PS 296
__global__ __launch_bounds__(256, 4)
void attn_mfma_kernel(const u16* __restrict__ q, const u16* __restrict__ k,
                      const u16* __restrict__ vT, u16* __restrict__ o) {
    __shared__ __align__(16) u16 sP[64 * ATT_PS];
    __shared__ float sInv[64];

    const int t = threadIdx.x;
    const int wave = t >> 6, lane = t & 63;
    const int quad = lane >> 4, l16 = lane & 15;

    const int lid = blockIdx.x;
    const int g = lid / 40, local = lid - g * 40;
    const int qt = local >> 3, x = local & 7;
    const int hb = g * 8 + x;
    const int h = hb & (H_CNT - 1), b = hb >> 4;
    const int q0 = qt * 64;
    const size_t head = (size_t)b * N_SEQ * D_DIM + (size_t)h * HD_DIM;

    int qrow = q0 + wave * 16 + l16; if (qrow > N_SEQ - 1) qrow = N_SEQ - 1;
    const u16* qp = q + head + (size_t)qrow * D_DIM + quad * 8;
    bf16x8 qf0 = *(const bf16x8*)(qp);
    bf16x8 qf1 = *(const bf16x8*)(qp + 32);

    f32x4 s[5][4];
#pragma unroll
    for (int kt = 0; kt < 5; ++kt) {
        const int ntMax = (kt == 4) ? 2 : 4;
#pragma unroll
        for (int nt = 0; nt < 4; ++nt) {
            if (nt >= ntMax) continue;
            s[kt][nt] = {0.f, 0.f, 0.f, 0.f};
            int key = kt * 64 + nt * 16 + l16;
            if (key > N_SEQ - 1) key = N_SEQ - 1;
            const u16* kr = k + head + (size_t)key * D_DIM + quad * 8;
            bf16x8 b0 = *(const bf16x8*)(kr);
            bf16x8 b1 = *(const bf16x8*)(kr + 32);
            s[kt][nt] = __builtin_amdgcn_mfma_f32_16x16x32_bf16(qf0, b0, s[kt][nt], 0, 0, 0);
            s[kt][nt] = __builtin_amdgcn_mfma_f32_16x16x32_bf16(qf1, b1, s[kt][nt], 0, 0, 0);
        }
    }

#pragma unroll
    for (int i = 0; i < 4; ++i) {
        float mx = -1e30f;
#pragma unroll
        for (int kt = 0; kt < 5; ++kt) {
            const int ntMax = (kt == 4) ? 2 : 4;
#pragma unroll
            for (int nt = 0; nt < 4; ++nt) {
                if (nt >= ntMax) continue;
                const bool valid = (kt < 4) || (nt == 0 && l16 == 0);
                if (valid) mx = fmaxf(mx, s[kt][nt][i]);
            }
        }
        mx = fmaxf(mx, __shfl_xor(mx, 1, 64));
        mx = fmaxf(mx, __shfl_xor(mx, 2, 64));
        mx = fmaxf(mx, __shfl_xor(mx, 4, 64));
        mx = fmaxf(mx, __shfl_xor(mx, 8, 64));
        float sum = 0.f;
        const int prow = wave * 16 + quad * 4 + i;
#pragma unroll
        for (int kt = 0; kt < 5; ++kt) {
            const int ntMax = (kt == 4) ? 2 : 4;
#pragma unroll
            for (int nt = 0; nt < 4; ++nt) {
                if (nt >= ntMax) continue;
                const bool valid = (kt < 4) || (nt == 0 && l16 == 0);
                float pv = 0.f;
                if (valid) { pv = __expf(s[kt][nt][i] - mx); sum += pv; }
                sP[prow * ATT_PS + kt * 64 + nt * 16 + l16] = f2b(pv);
            }
        }
        sum += __shfl_xor(sum, 1, 64);
        sum += __shfl_xor(sum, 2, 64);
        sum += __shfl_xor(sum, 4, 64);
        sum += __shfl_xor(sum, 8, 64);
        if (l16 == 0) sInv[prow] = 1.0f / sum;
    }
    __syncthreads();   // required: orders u16 stores vs bf16-vector loads of sP

    f32x4 oacc[4] = {{0.f,0.f,0.f,0.f},{0.f,0.f,0.f,0.f},
                     {0.f,0.f,0.f,0.f},{0.f,0.f,0.f,0.f}};
    const u16* vhead = vT + ((size_t)b * D_DIM + h * HD_DIM) * VT_NP;
    const int prr = wave * 16 + l16;
#pragma unroll
    for (int kt = 0; kt < 5; ++kt) {
        const int j0 = kt * 64;
        bf16x8 p0 = *(const bf16x8*)(sP + prr * ATT_PS + j0 + quad * 8);
        bf16x8 p1;
        if (kt < 4) p1 = *(const bf16x8*)(sP + prr * ATT_PS + j0 + quad * 8 + 32);
#pragma unroll
        for (int nt = 0; nt < 4; ++nt) {
            const u16* vr = vhead + (size_t)(nt * 16 + l16) * VT_NP + j0 + quad * 8;
            bf16x8 b0 = *(const bf16x8*)(vr);
            oacc[nt] = __builtin_amdgcn_mfma_f32_16x16x32_bf16(p0, b0, oacc[nt], 0, 0, 0);
            if (kt < 4) {
                bf16x8 b1 = *(const bf16x8*)(vr + 32);
                oacc[nt] = __builtin_amdgcn_mfma_f32_16x16x32_bf16(p1, b1, oacc[nt], 0, 0, 0);
            }
        }
    }
#pragma unroll
    for (int nt = 0; nt < 4; ++nt) {
#pragma unroll
        for (int i = 0; i < 4; ++i) {
            const int mrow = wave * 16 + quad * 4 + i;
            const int m = q0 + mrow;
            if (m < N_SEQ) {
                o[head + (size_t)m * D_DIM + nt * 16 + l16] =
                    f2b(oacc[nt][i] * sInv[mrow]);
            }
        }
    }
}

extern "C" void kernel_launch(void* const* d_in, const int* in_sizes, int n_in,
                              void* d_out, int out_size, void* d_ws, size_t ws_size,
                              hipStream_t stream) {
    const float* hs   = (const float*)d_in[0];
    const float* ln1w = (const float*)d_in[1];
    const float* ln1b = (const float*)d_in[2];
    const float* wq   = (const float*)d_in[3];
    const float* bq   = (const float*)d_in[4];
    const float* wk   = (const float*)d_in[5];
    const float* bk   = (const float*)d_in[6];
    const float* wv   = (const float*)d_in[7];
    const float* bv   = (const float*)d_in[8];
    const float* wo   = (const float*)d_in[9];
    const float* bo   = (const float*)d_in[10];
    const float* ln2w = (const float*)d_in[11];
    const float* ln2b = (const float*)d_in[12];
    const float* w1   = (const float*)d_in[13];
    const float* b1   = (const float*)d_in[14];
    const float* w2   = (const float*)d_in[15];
    const float* b2   = (const float*)d_in[16];

    char* p = (char*)d_ws;
    size_t off = 0;
    auto alloc = [&](size_t bytes) {
        char* r = p + off;
        off += (bytes + 255) & ~(size_t)255;
        return (void*)r;
    };
    const int M = M_TOK;
    // bf16 weight block: contiguous (cvt_all writes linearly): wqkv | wo
    u16* wqkvb = (u16*)alloc((size_t)3 * D_DIM * D_DIM * 2);
    u16* wob   = (u16*)alloc((size_t)D_DIM * D_DIM * 2);
    u8*  w1i8  = (u8*) alloc((size_t)FF_DIM * D_DIM);
    u8*  w2i8  = (u8*) alloc((size_t)D_DIM * FF_DIM);
    float* bqkv = (float*)alloc((size_t)3 * D_DIM * 4);
    u16*  x_ln = (u16*) alloc((size_t)M * D_DIM * 2);
    u16*  qb   = (u16*) alloc((size_t)M * D_DIM * 2);
    u16*  kb   = (u16*) alloc((size_t)M * D_DIM * 2);
    u16*  vTb  = (u16*) alloc((size_t)B_SZ * D_DIM * VT_NP * 2);
    u16*  ab   = (u16*) alloc((size_t)M * D_DIM * 2);
    float* hid = (float*)alloc((size_t)M * D_DIM * 4);
    // i8 aliases (regions dead after o-proj): h1i8 over qb+kb (42 MB), x2i8 over ab
    u8* h1i8 = (u8*)qb;
    u8* x2i8 = (u8*)ab;

    const int nDD = D_DIM * D_DIM, nFD = FF_DIM * D_DIM;
    const int WB8 = (4 * nDD) / 8, WF8 = (2 * nFD) / 8;
    cvt_all_kernel<<<(WB8 + WF8 + 3 * D_DIM + 255) / 256, 256, 0, stream>>>(
        wq, wk, wv, wo, w1, w2, bq, bk, bv, wqkvb, w1i8, w2i8, bqkv);

    ln_kernel<false><<<M, 256, 0, stream>>>(hs, ln1w, ln1b, x_ln);

    const int gM256 = (M + 255) / 256;            // 41
    gemm256_kernel<5><<<gM256 * (3 * D_DIM / 256), 512, 0, stream>>>(
        x_ln, wqkvb, bqkv, nullptr, qb, kb, vTb, M, 3 * D_DIM, D_DIM);

    attn_mfma_kernel<<<5 * H_CNT * B_SZ, 256, 0, stream>>>(qb, kb, vTb, ab);

    gemm256_kernel<2><<<gM256 * (D_DIM / 256), 512, 0, stream>>>(
        ab, wob, bo, hs, hid, nullptr, nullptr, M, D_DIM, D_DIM);

    ln_kernel<true><<<M, 256, 0, stream>>>(hid, ln2w, ln2b, x2i8);

    const int gM = (M + 127) / 128;  // 81
    dim3 gF(gM, FF_DIM / 128);       // 81 x 32
    gemm_i8_kernel<3><<<gF, 256, 0, stream>>>(x2i8, w1i8, b1, nullptr, h1i8,
                                              M, FF_DIM, D_DIM, 16);
    dim3 gD(gM, D_DIM / 128);        // 81 x 8
    gemm_i8_kernel<2><<<gD, 256, 0, stream>>>(h1i8, w2i8, b2, hid, (float*)d_out,
                                              M, D_DIM, FF_DIM, 4);
}

// Round 2
// 609.694 us; speedup vs baseline: 1.0433x; 1.0031x over previous
//
#include <hip/hip_runtime.h>
#include <math.h>

#define D_DIM 1024
#define FF_DIM 4096
#define N_SEQ 257
#define B_SZ 40
#define H_CNT 16
#define HD_DIM 64
#define M_TOK (B_SZ * N_SEQ)   // 10280
#define VT_NP 320               // padded key dim for vT (keys contiguous)

typedef unsigned short u16;
typedef unsigned char u8;
typedef __bf16 bf16x8 __attribute__((ext_vector_type(8)));
typedef float f32x4 __attribute__((ext_vector_type(4)));
typedef int i32x4 __attribute__((ext_vector_type(4)));

__device__ __forceinline__ float b2f(u16 u) {
    union { unsigned int i; float f; } x; x.i = ((unsigned int)u) << 16; return x.f;
}
__device__ __forceinline__ u16 f2b(float f) {
    union { float f; unsigned int i; } x; x.f = f;
    unsigned int r = x.i + 0x7FFFu + ((x.i >> 16) & 1u);  // round-to-nearest-even
    return (u16)(r >> 16);
}
// float -> signed i8 (RNE, clamp +-127), returned as low byte
__device__ __forceinline__ unsigned q8(float f, float s) {
    int q = __float2int_rn(f * s);
    q = q < -127 ? -127 : (q > 127 ? 127 : q);
    return (unsigned)q & 0xFFu;
}

// async global->LDS 16B (dest = wave-uniform base + lane*16; contiguous layout)
__device__ __forceinline__ void g2lds16(const void* g, void* l) {
    __builtin_amdgcn_global_load_lds(
        (const __attribute__((address_space(1))) void*)g,
        (__attribute__((address_space(3))) void*)l,
        16, 0, 0);
}

// ---------------- fused weight conversion + bias concat ----------------
// bf16 dst (contiguous): wqkv[3*nDD] | wo[nDD].  i8 dst: w1i8 (x1024), w2i8 (x1024).
__global__ __launch_bounds__(256)
void cvt_all_kernel(const float* __restrict__ wq, const float* __restrict__ wk,
                    const float* __restrict__ wv, const float* __restrict__ wo,
                    const float* __restrict__ w1, const float* __restrict__ w2,
                    const float* __restrict__ bq, const float* __restrict__ bk,
                    const float* __restrict__ bv,
                    u16* __restrict__ wdst, u8* __restrict__ w1i8,
                    u8* __restrict__ w2i8, float* __restrict__ bqkv) {
    const int nDD = D_DIM * D_DIM, nFD = FF_DIM * D_DIM;
    const int WB8 = (4 * nDD) / 8;       // bf16 8-elem chunks
    const int WF8 = (2 * nFD) / 8;       // i8 8-elem chunks
    const int tid = blockIdx.x * 256 + threadIdx.x;
    if (tid < WB8) {
        const int i = tid * 8;
        const float* src; int s;
        if (i < nDD)          { src = wq; s = i; }
        else if (i < 2 * nDD) { src = wk; s = i - nDD; }
        else if (i < 3 * nDD) { src = wv; s = i - 2 * nDD; }
        else                  { src = wo; s = i - 3 * nDD; }
        float4 a = *(const float4*)(src + s);
        float4 b = *(const float4*)(src + s + 4);
        u16 o[8] = {f2b(a.x), f2b(a.y), f2b(a.z), f2b(a.w),
                    f2b(b.x), f2b(b.y), f2b(b.z), f2b(b.w)};
        *(uint4*)(wdst + i) = *(const uint4*)o;
    } else if (tid < WB8 + WF8) {
        const int j = (tid - WB8) * 8;
        const float* src; u8* dst; int s;
        if (j < nFD) { src = w1; dst = w1i8; s = j; }
        else         { src = w2; dst = w2i8; s = j - nFD; }
        float4 a = *(const float4*)(src + s);
        float4 b = *(const float4*)(src + s + 4);
        const float sc = 1024.f;
        unsigned lo = q8(a.x, sc) | (q8(a.y, sc) << 8) |
                      (q8(a.z, sc) << 16) | (q8(a.w, sc) << 24);
        unsigned hi = q8(b.x, sc) | (q8(b.y, sc) << 8) |
                      (q8(b.z, sc) << 16) | (q8(b.w, sc) << 24);
        uint2 pk = {lo, hi};
        *(uint2*)(dst + s) = pk;
    } else {
        const int j = tid - WB8 - WF8;
        if (j < 3 * D_DIM) {
            bqkv[j] = (j < D_DIM) ? bq[j]
                    : (j < 2 * D_DIM ? bk[j - D_DIM] : bv[j - 2 * D_DIM]);
        }
    }
}

// ---------------- LayerNorm: one block (256 thr) per token row of 1024 ----------------
// I8OUT=false -> bf16 out (u16*), I8OUT=true -> i8 out x16 (u8*)
template <bool I8OUT>
__global__ __launch_bounds__(256)
void ln_kernel(const float* __restrict__ in, const float* __restrict__ w,
               const float* __restrict__ b, void* __restrict__ out) {
    const int row = blockIdx.x;
    const int t = threadIdx.x;
    const size_t base = (size_t)row * D_DIM;
    float x[4];
#pragma unroll
    for (int i = 0; i < 4; ++i) x[i] = in[base + t + i * 256];
    float s  = x[0] + x[1] + x[2] + x[3];
    float ss = x[0]*x[0] + x[1]*x[1] + x[2]*x[2] + x[3]*x[3];
#pragma unroll
    for (int o = 32; o > 0; o >>= 1) {
        s  += __shfl_xor(s, o, 64);
        ss += __shfl_xor(ss, o, 64);
    }
    __shared__ float sh_s[4], sh_ss[4];
    const int wave = t >> 6, lane = t & 63;
    if (lane == 0) { sh_s[wave] = s; sh_ss[wave] = ss; }
    __syncthreads();
    float S  = sh_s[0] + sh_s[1] + sh_s[2] + sh_s[3];
    float SS = sh_ss[0] + sh_ss[1] + sh_ss[2] + sh_ss[3];
    float mean = S * (1.0f / D_DIM);
    float var  = SS * (1.0f / D_DIM) - mean * mean;
    float rstd = rsqrtf(var + 1e-5f);
#pragma unroll
    for (int i = 0; i < 4; ++i) {
        int idx = t + i * 256;
        float y = (x[i] - mean) * rstd * w[idx] + b[idx];
        if (I8OUT) ((u8*)out)[base + idx]  = (u8)q8(y, 16.f);
        else       ((u16*)out)[base + idx] = f2b(y);
    }
}

// ---------------- bf16 GEMM 256x256, merged-phase counted-vmcnt schedule -------------
// 8 waves (512 thr): wr in {0,1} owns 128 rows, wc in {0..3} owns 64 cols.
// LDS: 8 slots x 16KB, slot = buf*4 + kh (A) / buf*4 + 2 + kh (B); slot = [256 rows][32 k]
// bf16, 64B rows. Swizzle: 16B chunk c of row r holds global k-chunk c ^ ((r>>1)&3)
// (pre-swizzled GLOBAL source, linear LDS dest; read chunk = quad ^ ((l16>>1)&3)) ->
// per quarter-wave each 4-bank group hit exactly 2x = conflict-free (m136: 2-way free).
// 4 merged phases per iteration (2 K-tiles): each phase = {12 ds_read_b128 | stage one
// (A,B) K-half pair (4 global_load_lds) | 32 MFMA} closed by ONE vmcnt(8) + ONE barrier.
// Hazards: reads at phase F use slots staged at F-3 (forced complete by F-1's vmcnt(8),
// published by its barrier); stages at F overwrite the slot read at F-1 (reads lgkm-
// complete before that barrier). Never vmcnt(0) in the main loop.
// MODE 2: out_f32 = extra_f32 + acc + bias (o-proj + residual)
// MODE 5: QKV fused (N=3072): seg0 -> q*0.125, seg1 -> k, seg2 -> vT scatter
#define G256_PHASE(BUF, KH, KT_S, KH_S, DOSTAGE)                                     \
  {                                                                                  \
    const u16* sa_ = lds + ((BUF) * 4 + (KH)) * 8192;                                \
    const u16* sb_ = lds + ((BUF) * 4 + 2 + (KH)) * 8192;                            \
    bf16x8 af[4], bfv[4];                                                            \
    _Pragma("unroll") for (int mf = 0; mf < 4; ++mf)                                 \
        af[mf] = *(const bf16x8*)(sa_ + (wr * 128 + mf * 16 + l16) * 32 + xch);      \
    _Pragma("unroll") for (int nf = 0; nf < 4; ++nf)                                 \
        bfv[nf] = *(const bf16x8*)(sb_ + (wc * 64 + nf * 16 + l16) * 32 + xch);      \
    if (DOSTAGE) { stageA(KT_S, KH_S); stageB(KT_S, KH_S); }                         \
    __builtin_amdgcn_s_setprio(1);                                                   \
    _Pragma("unroll") for (int mf = 0; mf < 4; ++mf)                                 \
      _Pragma("unroll") for (int nf = 0; nf < 4; ++nf)                               \
          acc[mf][nf] = __builtin_amdgcn_mfma_f32_16x16x32_bf16(                     \
              af[mf], bfv[nf], acc[mf][nf], 0, 0, 0);                                \
    _Pragma("unroll") for (int mf = 0; mf < 4; ++mf)                                 \
        af[mf] = *(const bf16x8*)(sa_ + (wr * 128 + 64 + mf * 16 + l16) * 32 + xch); \
    _Pragma("unroll") for (int mf = 0; mf < 4; ++mf)                                 \
      _Pragma("unroll") for (int nf = 0; nf < 4; ++nf)                               \
          acc[4 + mf][nf] = __builtin_amdgcn_mfma_f32_16x16x32_bf16(                 \
              af[mf], bfv[nf], acc[4 + mf][nf], 0, 0, 0);                            \
    __builtin_amdgcn_s_setprio(0);                                                   \
    asm volatile("s_waitcnt vmcnt(8)" ::: "memory");                                 \
    __builtin_amdgcn_s_barrier();                                                    \
    asm volatile("" ::: "memory");                                                   \
  }

template <int MODE>
__global__ __launch_bounds__(512, 2)
void gemm256_kernel(const u16* __restrict__ A, const u16* __restrict__ Bt,
                    const float* __restrict__ bias, const float* __restrict__ extra,
                    void* __restrict__ out, u16* __restrict__ out2, u16* __restrict__ out3,
                    int M, int N, int K) {
    __shared__ __align__(16) u16 lds[8 * 8192];   // 128 KiB
    const int t = threadIdx.x;
    const int lane = t & 63, wave = t >> 6;
    const int quad = lane >> 4, l16 = lane & 15;
    const int wr = wave >> 2, wc = wave & 3;
    // swizzled read chunk (u16 units): rows are base+l16 with base%16==0 ->
    // (row>>1)&3 == (l16>>1)&3 for all fragments
    const int xch = (quad ^ ((l16 >> 1) & 3)) * 8;

    // bijective XCD swizzle (m204: grid not %8==0)
    const int nwg = gridDim.x;
    const int nT = N >> 8;
    const int orig = blockIdx.x;
    const int xcd = orig & 7, loc = orig >> 3;
    const int qq = nwg >> 3, rr = nwg & 7;
    const int wgid = (xcd < rr ? xcd * (qq + 1) : rr * (qq + 1) + (xcd - rr) * qq) + loc;
    const int m0 = (wgid / nT) * 256;
    const int n0 = (wgid % nT) * 256;

    // staging: chunk c in [0,1024): row=c>>2, LDS chunk=c&3 (linear dest);
    // global source k-chunk = (c&3) ^ ((row>>1)&3) = (c&3) ^ ((c>>3)&3)
    auto stageA = [&](int kt, int kh) {
#pragma unroll
        for (int l = 0; l < 2; ++l) {
            const int c = l * 512 + t;
            int gr = m0 + (c >> 2); if (gr > M - 1) gr = M - 1;
            const int sg = (c & 3) ^ ((c >> 3) & 3);
            g2lds16(A + (size_t)gr * K + kt * 64 + kh * 32 + sg * 8,
                    lds + ((kt & 1) * 4 + kh) * 8192 + c * 8);
        }
    };
    auto stageB = [&](int kt, int kh) {
#pragma unroll
        for (int l = 0; l < 2; ++l) {
            const int c = l * 512 + t;
            const int sg = (c & 3) ^ ((c >> 3) & 3);
            g2lds16(Bt + (size_t)(n0 + (c >> 2)) * K + kt * 64 + kh * 32 + sg * 8,
                    lds + ((kt & 1) * 4 + 2 + kh) * 8192 + c * 8);
        }
    };

    f32x4 acc[8][4];
#pragma unroll
    for (int mi = 0; mi < 8; ++mi)
#pragma unroll
        for (int nf = 0; nf < 4; ++nf) acc[mi][nf] = {0.f, 0.f, 0.f, 0.f};

    // prologue: stage the 3 (A,B) half-pairs read by phases 0,1,2 (12 loads in flight)
    stageA(0, 0); stageB(0, 0); stageA(0, 1); stageB(0, 1); stageA(1, 0); stageB(1, 0);
    asm volatile("s_waitcnt vmcnt(8)" ::: "memory");   // oldest 4 = (0,0) A+B landed
    __builtin_amdgcn_s_barrier();
    asm volatile("" ::: "memory");

    const int NIT = K >> 7;                        // 2 K-tiles (BK=64) per iteration
    for (int i = 0; i < NIT; ++i) {
        const int kt0 = 2 * i;
        const bool more = (i < NIT - 1);
        G256_PHASE(0, 0, kt0 + 1, 1, true)
        G256_PHASE(0, 1, kt0 + 2, 0, more)
        G256_PHASE(1, 0, kt0 + 2, 1, more)
        G256_PHASE(1, 1, kt0 + 3, 0, more)
    }

    // epilogue: C/D layout col=l16, row=quad*4+i (verified mapping)
#pragma unroll
    for (int mi = 0; mi < 8; ++mi) {
#pragma unroll
        for (int nf = 0; nf < 4; ++nf) {
            const int n = n0 + wc * 64 + nf * 16 + l16;
            const float bvf = bias[n];
#pragma unroll
            for (int i2 = 0; i2 < 4; ++i2) {
                const int m = m0 + wr * 128 + mi * 16 + quad * 4 + i2;
                if (m >= M) continue;
                float v = acc[mi][nf][i2] + bvf;
                if (MODE == 2) {
                    const size_t idx = (size_t)m * N + n;
                    ((float*)out)[idx] = extra[idx] + v;
                } else {  // MODE 5
                    const int seg = n >> 10, nl = n & 1023;
                    if (seg == 0) {
                        ((u16*)out)[(size_t)m * D_DIM + nl] = f2b(v * 0.125f);
                    } else if (seg == 1) {
                        out2[(size_t)m * D_DIM + nl] = f2b(v);
                    } else {
                        const int bb = m / N_SEQ;
                        const int tt = m - bb * N_SEQ;
                        out3[((size_t)bb * D_DIM + nl) * VT_NP + tt] = f2b(v);
                    }
                }
            }
        }
    }
}

// ---------------- i8 GEMM 128x128, BK=128, mfma_i32_16x16x64_i8 ----------------
// A i8 [M,K] (scale sA_inv folded in epilogue), Bt i8 [N,K] (x1024).
// MODE 2: out_f32 = extra_f32 + acc/32768 + bias   (fc2 + residual -> d_out)
// MODE 3: out_i8  = quickgelu(acc/16384 + bias) x32  (fc1 -> h1i8)
template <int MODE>
__global__ __launch_bounds__(256)
void gemm_i8_kernel(const u8* __restrict__ A, const u8* __restrict__ Bt,
                    const float* __restrict__ bias, const float* __restrict__ extra,
                    void* __restrict__ out, int M, int N, int K, int sw) {
    __shared__ __align__(16) u8 sA[128 * 128];   // 16 KB
    __shared__ __align__(16) u8 sB[128 * 128];   // 16 KB
    const int t = threadIdx.x;

    const int nM = gridDim.x, nN = gridDim.y;
    const int lid   = blockIdx.y * nM + blockIdx.x;
    const int csz   = sw * nN;
    const int chunk = lid / csz;
    const int rem   = lid - chunk * csz;
    const int n0 = (rem % nN) * 128;
    const int m0 = (chunk * sw + rem / nN) * 128;

    const int wave = t >> 6, lane = t & 63;
    const int quad = lane >> 4, l16 = lane & 15;
    const int wm = (wave >> 1) * 64, wn = (wave & 1) * 64;

    const u8* gA[4]; const u8* gB[4]; u8* lA[4]; u8* lB[4];
#pragma unroll
    for (int i = 0; i < 4; ++i) {
        const int c = i * 256 + t;
        const int row = c >> 3;
        const int sg = (c & 7) ^ (row & 7);
        int gr = m0 + row; if (gr > M - 1) gr = M - 1;
        gA[i] = A  + (size_t)gr * K + sg * 16;
        gB[i] = Bt + (size_t)(n0 + row) * K + sg * 16;
        lA[i] = sA + c * 16;
        lB[i] = sB + c * 16;
    }

    i32x4 acc[4][4];
#pragma unroll
    for (int mt = 0; mt < 4; ++mt)
#pragma unroll
        for (int nt = 0; nt < 4; ++nt) acc[mt][nt] = {0, 0, 0, 0};

    for (int k0 = 0; k0 < K; k0 += 128) {
        __syncthreads();
#pragma unroll
        for (int i = 0; i < 4; ++i) g2lds16(gA[i] + k0, lA[i]);
#pragma unroll
        for (int i = 0; i < 4; ++i) g2lds16(gB[i] + k0, lB[i]);
        __syncthreads();
#pragma unroll
        for (int j = 0; j < 2; ++j) {
            i32x4 af[4], bfr[4];
#pragma unroll
            for (int mt = 0; mt < 4; ++mt) {
                const int r = wm + mt * 16 + l16;
                af[mt] = *(const i32x4*)(sA + r * 128 + (((j * 4 + quad) ^ (r & 7)) * 16));
            }
#pragma unroll
            for (int nt = 0; nt < 4; ++nt) {
                const int n = wn + nt * 16 + l16;
                bfr[nt] = *(const i32x4*)(sB + n * 128 + (((j * 4 + quad) ^ (n & 7)) * 16));
            }
#pragma unroll
            for (int mt = 0; mt < 4; ++mt)
#pragma unroll
                for (int nt = 0; nt < 4; ++nt)
                    acc[mt][nt] = __builtin_amdgcn_mfma_i32_16x16x64_i8(
                        af[mt], bfr[nt], acc[mt][nt], 0, 0, 0);
        }
    }

    const float sc = (MODE == 2) ? (1.f / 32768.f) : (1.f / 16384.f);
#pragma unroll
    for (int mt = 0; mt < 4; ++mt) {
#pragma unroll
        for (int nt = 0; nt < 4; ++nt) {
            const int n = n0 + wn + nt * 16 + l16;
            const float bvf = bias[n];
#pragma unroll
            for (int i = 0; i < 4; ++i) {
                const int m = m0 + wm + quad * 4 + i + mt * 16;
                if (m >= M) continue;
                float v = (float)acc[mt][nt][i] * sc + bvf;
                if (MODE == 2) {
                    const size_t idx = (size_t)m * N + n;
                    ((float*)out)[idx] = extra[idx] + v;
                } else {  // MODE 3: quickgelu -> i8 x32
                    float g = v / (1.0f + __expf(-1.702f * v));
                    ((u8*)out)[(size_t)m * N + n] = (u8)q8(g, 32.f);
                }
            }
        }
    }
}

// ---------------- MFMA attention v4 (unchanged) ----------------
#define ATT_PS 296
__global__ __launch_bounds__(256, 4)
void attn_mfma_kernel(const u16* __restrict__ q, const u16* __restrict__ k,
                      const u16* __restrict__ vT, u16* __restrict__ o) {
    __shared__ __align__(16) u16 sP[64 * ATT_PS];
    __shared__ float sInv[64];

    const int t = threadIdx.x;
    const int wave = t >> 6, lane = t & 63;
    const int quad = lane >> 4, l16 = lane & 15;

    const int lid = blockIdx.x;
    const int g = lid / 40, local = lid - g * 40;
    const int qt = local >> 3, x = local & 7;
    const int hb = g * 8 + x;
    const int h = hb & (H_CNT - 1), b = hb >> 4;
    const int q0 = qt * 64;
    const size_t head = (size_t)b * N_SEQ * D_DIM + (size_t)h * HD_DIM;

    int qrow = q0 + wave * 16 + l16; if (qrow > N_SEQ - 1) qrow = N_SEQ - 1;
    const u16* qp = q + head + (size_t)qrow * D_DIM + quad * 8;
    bf16x8 qf0 = *(const bf16x8*)(qp);
    bf16x8 qf1 = *(const bf16x8*)(qp + 32);

    f32x4 s[5][4];
#pragma unroll
    for (int kt = 0; kt < 5; ++kt) {
        const int ntMax = (kt == 4) ? 2 : 4;
#pragma unroll
        for (int nt = 0; nt < 4; ++nt) {
            if (nt >= ntMax) continue;
            s[kt][nt] = {0.f, 0.f, 0.f, 0.f};
            int key = kt * 64 + nt * 16 + l16;
            if (key > N_SEQ - 1) key = N_SEQ - 1;
            const u16* kr = k + head + (size_t)key * D_DIM + quad * 8;
            bf16x8 b0 = *(const bf16x8*)(kr);
            bf16x8 b1 = *(const bf16x8*)(kr + 32);
            s[kt][nt] = __builtin_amdgcn_mfma_f32_16x16x32_bf16(qf0, b0, s[kt][nt], 0, 0, 0);
            s[kt][nt] = __builtin_amdgcn_mfma_f32_16x16x32_bf16(qf1, b1, s[kt][nt], 0, 0, 0);
        }
    }

#pragma unroll
    for (int i = 0; i < 4; ++i) {
        float mx = -1e30f;
#pragma unroll
        for (int kt = 0; kt < 5; ++kt) {
            const int ntMax = (kt == 4) ? 2 : 4;
#pragma unroll
            for (int nt = 0; nt < 4; ++nt) {
                if (nt >= ntMax) continue;
                const bool valid = (kt < 4) || (nt == 0 && l16 == 0);
                if (valid) mx = fmaxf(mx, s[kt][nt][i]);
            }
        }
        mx = fmaxf(mx, __shfl_xor(mx, 1, 64));
        mx = fmaxf(mx, __shfl_xor(mx, 2, 64));
        mx = fmaxf(mx, __shfl_xor(mx, 4, 64));
        mx = fmaxf(mx, __shfl_xor(mx, 8, 64));
        float sum = 0.f;
        const int prow = wave * 16 + quad * 4 + i;
#pragma unroll
        for (int kt = 0; kt < 5; ++kt) {
            const int ntMax = (kt == 4) ? 2 : 4;
#pragma unroll
            for (int nt = 0; nt < 4; ++nt) {
                if (nt >= ntMax) continue;
                const bool valid = (kt < 4) || (nt == 0 && l16 == 0);
                float pv = 0.f;
                if (valid) { pv = __expf(s[kt][nt][i] - mx); sum += pv; }
                sP[prow * ATT_PS + kt * 64 + nt * 16 + l16] = f2b(pv);
            }
        }
        sum += __shfl_xor(sum, 1, 64);
        sum += __shfl_xor(sum, 2, 64);
        sum += __shfl_xor(sum, 4, 64);
        sum += __shfl_xor(sum, 8, 64);
        if (l16 == 0) sInv[prow] = 1.0f / sum;
    }
    __syncthreads();   // required: orders u16 stores vs bf16-vector loads of sP

    f32x4 oacc[4] = {{0.f,0.f,0.f,0.f},{0.f,0.f,0.f,0.f},
                     {0.f,0.f,0.f,0.f},{0.f,0.f,0.f,0.f}};
    const u16* vhead = vT + ((size_t)b * D_DIM + h * HD_DIM) * VT_NP;
    const int prr = wave * 16 + l16;
#pragma unroll
    for (int kt = 0; kt < 5; ++kt) {
        const int j0 = kt * 64;
        bf16x8 p0 = *(const bf16x8*)(sP + prr * ATT_PS + j0 + quad * 8);
        bf16x8 p1;
        if (kt < 4) p1 = *(const bf16x8*)(sP + prr * ATT_PS + j0 + quad * 8 + 32);
#pragma unroll
        for (int nt = 0; nt < 4; ++nt) {
            const u16* vr = vhead + (size_t)(nt * 16 + l16) * VT_NP + j0 + quad * 8;
            bf16x8 b0 = *(const bf16x8*)(vr);
            oacc[nt] = __builtin_amdgcn_mfma_f32_16x16x32_bf16(p0, b0, oacc[nt], 0, 0, 0);
            if (kt < 4) {
                bf16x8 b1 = *(const bf16x8*)(vr + 32);
                oacc[nt] = __builtin_amdgcn_mfma_f32_16x16x32_bf16(p1, b1, oacc[nt], 0, 0, 0);
            }
        }
    }
#pragma unroll
    for (int nt = 0; nt < 4; ++nt) {
#pragma unroll
        for (int i = 0; i < 4; ++i) {
            const int mrow = wave * 16 + quad * 4 + i;
            const int m = q0 + mrow;
            if (m < N_SEQ) {
                o[head + (size_t)m * D_DIM + nt * 16 + l16] =
                    f2b(oacc[nt][i] * sInv[mrow]);
            }
        }
    }
}

extern "C" void kernel_launch(void* const* d_in, const int* in_sizes, int n_in,
                              void* d_out, int out_size, void* d_ws, size_t ws_size,
                              hipStream_t stream) {
    const float* hs   = (const float*)d_in[0];
    const float* ln1w = (const float*)d_in[1];
    const float* ln1b = (const float*)d_in[2];
    const float* wq   = (const float*)d_in[3];
    const float* bq   = (const float*)d_in[4];
    const float* wk   = (const float*)d_in[5];
    const float* bk   = (const float*)d_in[6];
    const float* wv   = (const float*)d_in[7];
    const float* bv   = (const float*)d_in[8];
    const float* wo   = (const float*)d_in[9];
    const float* bo   = (const float*)d_in[10];
    const float* ln2w = (const float*)d_in[11];
    const float* ln2b = (const float*)d_in[12];
    const float* w1   = (const float*)d_in[13];
    const float* b1   = (const float*)d_in[14];
    const float* w2   = (const float*)d_in[15];
    const float* b2   = (const float*)d_in[16];

    char* p = (char*)d_ws;
    size_t off = 0;
    auto alloc = [&](size_t bytes) {
        char* r = p + off;
        off += (bytes + 255) & ~(size_t)255;
        return (void*)r;
    };
    const int M = M_TOK;
    // bf16 weight block: contiguous (cvt_all writes linearly): wqkv | wo
    u16* wqkvb = (u16*)alloc((size_t)3 * D_DIM * D_DIM * 2);
    u16* wob   = (u16*)alloc((size_t)D_DIM * D_DIM * 2);
    u8*  w1i8  = (u8*) alloc((size_t)FF_DIM * D_DIM);
    u8*  w2i8  = (u8*) alloc((size_t)D_DIM * FF_DIM);
    float* bqkv = (float*)alloc((size_t)3 * D_DIM * 4);
    u16*  x_ln = (u16*) alloc((size_t)M * D_DIM * 2);
    u16*  qb   = (u16*) alloc((size_t)M * D_DIM * 2);
    u16*  kb   = (u16*) alloc((size_t)M * D_DIM * 2);
    u16*  vTb  = (u16*) alloc((size_t)B_SZ * D_DIM * VT_NP * 2);
    u16*  ab   = (u16*) alloc((size_t)M * D_DIM * 2);
    float* hid = (float*)alloc((size_t)M * D_DIM * 4);
    // i8 aliases (regions dead after o-proj): h1i8 over qb+kb (42 MB), x2i8 over ab
    u8* h1i8 = (u8*)qb;
    u8* x2i8 = (u8*)ab;

    const int nDD = D_DIM * D_DIM, nFD = FF_DIM * D_DIM;
    const int WB8 = (4 * nDD) / 8, WF8 = (2 * nFD) / 8;
    cvt_all_kernel<<<(WB8 + WF8 + 3 * D_DIM + 255) / 256, 256, 0, stream>>>(
        wq, wk, wv, wo, w1, w2, bq, bk, bv, wqkvb, w1i8, w2i8, bqkv);

    ln_kernel<false><<<M, 256, 0, stream>>>(hs, ln1w, ln1b, x_ln);

    const int gM256 = (M + 255) / 256;            // 41
    gemm256_kernel<5><<<gM256 * (3 * D_DIM / 256), 512, 0, stream>>>(
        x_ln, wqkvb, bqkv, nullptr, qb, kb, vTb, M, 3 * D_DIM, D_DIM);

    attn_mfma_kernel<<<5 * H_CNT * B_SZ, 256, 0, stream>>>(qb, kb, vTb, ab);

    gemm256_kernel<2><<<gM256 * (D_DIM / 256), 512, 0, stream>>>(
        ab, wob, bo, hs, hid, nullptr, nullptr, M, D_DIM, D_DIM);

    ln_kernel<true><<<M, 256, 0, stream>>>(hid, ln2w, ln2b, x2i8);

    const int gM = (M + 127) / 128;  // 81
    dim3 gF(gM, FF_DIM / 128);       // 81 x 32
    gemm_i8_kernel<3><<<gF, 256, 0, stream>>>(x2i8, w1i8, b1, nullptr, h1i8,
                                              M, FF_DIM, D_DIM, 16);
    dim3 gD(gM, D_DIM / 128);        // 81 x 8
    gemm_i8_kernel<2><<<gD, 256, 0, stream>>>(h1i8, w2i8, b2, hid, (float*)d_out,
                                              M, D_DIM, FF_DIM, 4);
}

// Round 3
// 573.853 us; speedup vs baseline: 1.1084x; 1.0625x over previous
//
#include <hip/hip_runtime.h>
#include <math.h>

#define D_DIM 1024
#define FF_DIM 4096
#define N_SEQ 257
#define B_SZ 40
#define H_CNT 16
#define HD_DIM 64
#define M_TOK (B_SZ * N_SEQ)   // 10280
#define VT_NP 320               // padded key dim for vT (keys contiguous)

typedef unsigned short u16;
typedef unsigned char u8;
typedef __bf16 bf16x8 __attribute__((ext_vector_type(8)));
typedef float f32x4 __attribute__((ext_vector_type(4)));
typedef int i32x4 __attribute__((ext_vector_type(4)));

__device__ __forceinline__ float b2f(u16 u) {
    union { unsigned int i; float f; } x; x.i = ((unsigned int)u) << 16; return x.f;
}
__device__ __forceinline__ u16 f2b(float f) {
    union { float f; unsigned int i; } x; x.f = f;
    unsigned int r = x.i + 0x7FFFu + ((x.i >> 16) & 1u);  // round-to-nearest-even
    return (u16)(r >> 16);
}
// float -> signed i8 (RNE, clamp +-127), returned as low byte
__device__ __forceinline__ unsigned q8(float f, float s) {
    int q = __float2int_rn(f * s);
    q = q < -127 ? -127 : (q > 127 ? 127 : q);
    return (unsigned)q & 0xFFu;
}

// async global->LDS 16B (dest = wave-uniform base + lane*16; contiguous layout)
__device__ __forceinline__ void g2lds16(const void* g, void* l) {
    __builtin_amdgcn_global_load_lds(
        (const __attribute__((address_space(1))) void*)g,
        (__attribute__((address_space(3))) void*)l,
        16, 0, 0);
}

// ---------------- fused weight conversion + bias concat ----------------
// bf16 dst (contiguous): wqkv[3*nDD] | wo[nDD].  i8 dst: w1i8 (x1024), w2i8 (x1024).
__global__ __launch_bounds__(256)
void cvt_all_kernel(const float* __restrict__ wq, const float* __restrict__ wk,
                    const float* __restrict__ wv, const float* __restrict__ wo,
                    const float* __restrict__ w1, const float* __restrict__ w2,
                    const float* __restrict__ bq, const float* __restrict__ bk,
                    const float* __restrict__ bv,
                    u16* __restrict__ wdst, u8* __restrict__ w1i8,
                    u8* __restrict__ w2i8, float* __restrict__ bqkv) {
    const int nDD = D_DIM * D_DIM, nFD = FF_DIM * D_DIM;
    const int WB8 = (4 * nDD) / 8;       // bf16 8-elem chunks
    const int WF8 = (2 * nFD) / 8;       // i8 8-elem chunks
    const int tid = blockIdx.x * 256 + threadIdx.x;
    if (tid < WB8) {
        const int i = tid * 8;
        const float* src; int s;
        if (i < nDD)          { src = wq; s = i; }
        else if (i < 2 * nDD) { src = wk; s = i - nDD; }
        else if (i < 3 * nDD) { src = wv; s = i - 2 * nDD; }
        else                  { src = wo; s = i - 3 * nDD; }
        float4 a = *(const float4*)(src + s);
        float4 b = *(const float4*)(src + s + 4);
        u16 o[8] = {f2b(a.x), f2b(a.y), f2b(a.z), f2b(a.w),
                    f2b(b.x), f2b(b.y), f2b(b.z), f2b(b.w)};
        *(uint4*)(wdst + i) = *(const uint4*)o;
    } else if (tid < WB8 + WF8) {
        const int j = (tid - WB8) * 8;
        const float* src; u8* dst; int s;
        if (j < nFD) { src = w1; dst = w1i8; s = j; }
        else         { src = w2; dst = w2i8; s = j - nFD; }
        float4 a = *(const float4*)(src + s);
        float4 b = *(const float4*)(src + s + 4);
        const float sc = 1024.f;
        unsigned lo = q8(a.x, sc) | (q8(a.y, sc) << 8) |
                      (q8(a.z, sc) << 16) | (q8(a.w, sc) << 24);
        unsigned hi = q8(b.x, sc) | (q8(b.y, sc) << 8) |
                      (q8(b.z, sc) << 16) | (q8(b.w, sc) << 24);
        uint2 pk = {lo, hi};
        *(uint2*)(dst + s) = pk;
    } else {
        const int j = tid - WB8 - WF8;
        if (j < 3 * D_DIM) {
            bqkv[j] = (j < D_DIM) ? bq[j]
                    : (j < 2 * D_DIM ? bk[j - D_DIM] : bv[j - 2 * D_DIM]);
        }
    }
}

// ---------------- LayerNorm: one block (256 thr) per token row of 1024 ----------------
// I8OUT=false -> bf16 out (u16*), I8OUT=true -> i8 out x16 (u8*)
template <bool I8OUT>
__global__ __launch_bounds__(256)
void ln_kernel(const float* __restrict__ in, const float* __restrict__ w,
               const float* __restrict__ b, void* __restrict__ out) {
    const int row = blockIdx.x;
    const int t = threadIdx.x;
    const size_t base = (size_t)row * D_DIM;
    float x[4];
#pragma unroll
    for (int i = 0; i < 4; ++i) x[i] = in[base + t + i * 256];
    float s  = x[0] + x[1] + x[2] + x[3];
    float ss = x[0]*x[0] + x[1]*x[1] + x[2]*x[2] + x[3]*x[3];
#pragma unroll
    for (int o = 32; o > 0; o >>= 1) {
        s  += __shfl_xor(s, o, 64);
        ss += __shfl_xor(ss, o, 64);
    }
    __shared__ float sh_s[4], sh_ss[4];
    const int wave = t >> 6, lane = t & 63;
    if (lane == 0) { sh_s[wave] = s; sh_ss[wave] = ss; }
    __syncthreads();
    float S  = sh_s[0] + sh_s[1] + sh_s[2] + sh_s[3];
    float SS = sh_ss[0] + sh_ss[1] + sh_ss[2] + sh_ss[3];
    float mean = S * (1.0f / D_DIM);
    float var  = SS * (1.0f / D_DIM) - mean * mean;
    float rstd = rsqrtf(var + 1e-5f);
#pragma unroll
    for (int i = 0; i < 4; ++i) {
        int idx = t + i * 256;
        float y = (x[i] - mean) * rstd * w[idx] + b[idx];
        if (I8OUT) ((u8*)out)[base + idx]  = (u8)q8(y, 16.f);
        else       ((u16*)out)[base + idx] = f2b(y);
    }
}

// ---------------- bf16 GEMM 256x256, merged-phase counted-vmcnt schedule -------------
// (unchanged from round 2; steady-state QKV <122us, bank conflicts 0)
#define G256_PHASE(BUF, KH, KT_S, KH_S, DOSTAGE)                                     \
  {                                                                                  \
    const u16* sa_ = lds + ((BUF) * 4 + (KH)) * 8192;                                \
    const u16* sb_ = lds + ((BUF) * 4 + 2 + (KH)) * 8192;                            \
    bf16x8 af[4], bfv[4];                                                            \
    _Pragma("unroll") for (int mf = 0; mf < 4; ++mf)                                 \
        af[mf] = *(const bf16x8*)(sa_ + (wr * 128 + mf * 16 + l16) * 32 + xch);      \
    _Pragma("unroll") for (int nf = 0; nf < 4; ++nf)                                 \
        bfv[nf] = *(const bf16x8*)(sb_ + (wc * 64 + nf * 16 + l16) * 32 + xch);      \
    if (DOSTAGE) { stageA(KT_S, KH_S); stageB(KT_S, KH_S); }                         \
    __builtin_amdgcn_s_setprio(1);                                                   \
    _Pragma("unroll") for (int mf = 0; mf < 4; ++mf)                                 \
      _Pragma("unroll") for (int nf = 0; nf < 4; ++nf)                               \
          acc[mf][nf] = __builtin_amdgcn_mfma_f32_16x16x32_bf16(                     \
              af[mf], bfv[nf], acc[mf][nf], 0, 0, 0);                                \
    _Pragma("unroll") for (int mf = 0; mf < 4; ++mf)                                 \
        af[mf] = *(const bf16x8*)(sa_ + (wr * 128 + 64 + mf * 16 + l16) * 32 + xch); \
    _Pragma("unroll") for (int mf = 0; mf < 4; ++mf)                                 \
      _Pragma("unroll") for (int nf = 0; nf < 4; ++nf)                               \
          acc[4 + mf][nf] = __builtin_amdgcn_mfma_f32_16x16x32_bf16(                 \
              af[mf], bfv[nf], acc[4 + mf][nf], 0, 0, 0);                            \
    __builtin_amdgcn_s_setprio(0);                                                   \
    asm volatile("s_waitcnt vmcnt(8)" ::: "memory");                                 \
    __builtin_amdgcn_s_barrier();                                                    \
    asm volatile("" ::: "memory");                                                   \
  }

template <int MODE>
__global__ __launch_bounds__(512, 2)
void gemm256_kernel(const u16* __restrict__ A, const u16* __restrict__ Bt,
                    const float* __restrict__ bias, const float* __restrict__ extra,
                    void* __restrict__ out, u16* __restrict__ out2, u16* __restrict__ out3,
                    int M, int N, int K) {
    __shared__ __align__(16) u16 lds[8 * 8192];   // 128 KiB
    const int t = threadIdx.x;
    const int lane = t & 63, wave = t >> 6;
    const int quad = lane >> 4, l16 = lane & 15;
    const int wr = wave >> 2, wc = wave & 3;
    const int xch = (quad ^ ((l16 >> 1) & 3)) * 8;

    // bijective XCD swizzle (m204: grid not %8==0)
    const int nwg = gridDim.x;
    const int nT = N >> 8;
    const int orig = blockIdx.x;
    const int xcd = orig & 7, loc = orig >> 3;
    const int qq = nwg >> 3, rr = nwg & 7;
    const int wgid = (xcd < rr ? xcd * (qq + 1) : rr * (qq + 1) + (xcd - rr) * qq) + loc;
    const int m0 = (wgid / nT) * 256;
    const int n0 = (wgid % nT) * 256;

    auto stageA = [&](int kt, int kh) {
#pragma unroll
        for (int l = 0; l < 2; ++l) {
            const int c = l * 512 + t;
            int gr = m0 + (c >> 2); if (gr > M - 1) gr = M - 1;
            const int sg = (c & 3) ^ ((c >> 3) & 3);
            g2lds16(A + (size_t)gr * K + kt * 64 + kh * 32 + sg * 8,
                    lds + ((kt & 1) * 4 + kh) * 8192 + c * 8);
        }
    };
    auto stageB = [&](int kt, int kh) {
#pragma unroll
        for (int l = 0; l < 2; ++l) {
            const int c = l * 512 + t;
            const int sg = (c & 3) ^ ((c >> 3) & 3);
            g2lds16(Bt + (size_t)(n0 + (c >> 2)) * K + kt * 64 + kh * 32 + sg * 8,
                    lds + ((kt & 1) * 4 + 2 + kh) * 8192 + c * 8);
        }
    };

    f32x4 acc[8][4];
#pragma unroll
    for (int mi = 0; mi < 8; ++mi)
#pragma unroll
        for (int nf = 0; nf < 4; ++nf) acc[mi][nf] = {0.f, 0.f, 0.f, 0.f};

    stageA(0, 0); stageB(0, 0); stageA(0, 1); stageB(0, 1); stageA(1, 0); stageB(1, 0);
    asm volatile("s_waitcnt vmcnt(8)" ::: "memory");
    __builtin_amdgcn_s_barrier();
    asm volatile("" ::: "memory");

    const int NIT = K >> 7;                        // 2 K-tiles (BK=64) per iteration
    for (int i = 0; i < NIT; ++i) {
        const int kt0 = 2 * i;
        const bool more = (i < NIT - 1);
        G256_PHASE(0, 0, kt0 + 1, 1, true)
        G256_PHASE(0, 1, kt0 + 2, 0, more)
        G256_PHASE(1, 0, kt0 + 2, 1, more)
        G256_PHASE(1, 1, kt0 + 3, 0, more)
    }

    // epilogue: C/D layout col=l16, row=quad*4+i (verified mapping)
#pragma unroll
    for (int mi = 0; mi < 8; ++mi) {
#pragma unroll
        for (int nf = 0; nf < 4; ++nf) {
            const int n = n0 + wc * 64 + nf * 16 + l16;
            const float bvf = bias[n];
#pragma unroll
            for (int i2 = 0; i2 < 4; ++i2) {
                const int m = m0 + wr * 128 + mi * 16 + quad * 4 + i2;
                if (m >= M) continue;
                float v = acc[mi][nf][i2] + bvf;
                if (MODE == 2) {
                    const size_t idx = (size_t)m * N + n;
                    ((float*)out)[idx] = extra[idx] + v;
                } else {  // MODE 5
                    const int seg = n >> 10, nl = n & 1023;
                    if (seg == 0) {
                        ((u16*)out)[(size_t)m * D_DIM + nl] = f2b(v * 0.125f);
                    } else if (seg == 1) {
                        out2[(size_t)m * D_DIM + nl] = f2b(v);
                    } else {
                        const int bb = m / N_SEQ;
                        const int tt = m - bb * N_SEQ;
                        out3[((size_t)bb * D_DIM + nl) * VT_NP + tt] = f2b(v);
                    }
                }
            }
        }
    }
}

// ---------------- i8 GEMM 128x128, BK=128, mfma_i32_16x16x64_i8 (unchanged) --------
template <int MODE>
__global__ __launch_bounds__(256)
void gemm_i8_kernel(const u8* __restrict__ A, const u8* __restrict__ Bt,
                    const float* __restrict__ bias, const float* __restrict__ extra,
                    void* __restrict__ out, int M, int N, int K, int sw) {
    __shared__ __align__(16) u8 sA[128 * 128];   // 16 KB
    __shared__ __align__(16) u8 sB[128 * 128];   // 16 KB
    const int t = threadIdx.x;

    const int nM = gridDim.x, nN = gridDim.y;
    const int lid   = blockIdx.y * nM + blockIdx.x;
    const int csz   = sw * nN;
    const int chunk = lid / csz;
    const int rem   = lid - chunk * csz;
    const int n0 = (rem % nN) * 128;
    const int m0 = (chunk * sw + rem / nN) * 128;

    const int wave = t >> 6, lane = t & 63;
    const int quad = lane >> 4, l16 = lane & 15;
    const int wm = (wave >> 1) * 64, wn = (wave & 1) * 64;

    const u8* gA[4]; const u8* gB[4]; u8* lA[4]; u8* lB[4];
#pragma unroll
    for (int i = 0; i < 4; ++i) {
        const int c = i * 256 + t;
        const int row = c >> 3;
        const int sg = (c & 7) ^ (row & 7);
        int gr = m0 + row; if (gr > M - 1) gr = M - 1;
        gA[i] = A  + (size_t)gr * K + sg * 16;
        gB[i] = Bt + (size_t)(n0 + row) * K + sg * 16;
        lA[i] = sA + c * 16;
        lB[i] = sB + c * 16;
    }

    i32x4 acc[4][4];
#pragma unroll
    for (int mt = 0; mt < 4; ++mt)
#pragma unroll
        for (int nt = 0; nt < 4; ++nt) acc[mt][nt] = {0, 0, 0, 0};

    for (int k0 = 0; k0 < K; k0 += 128) {
        __syncthreads();
#pragma unroll
        for (int i = 0; i < 4; ++i) g2lds16(gA[i] + k0, lA[i]);
#pragma unroll
        for (int i = 0; i < 4; ++i) g2lds16(gB[i] + k0, lB[i]);
        __syncthreads();
#pragma unroll
        for (int j = 0; j < 2; ++j) {
            i32x4 af[4], bfr[4];
#pragma unroll
            for (int mt = 0; mt < 4; ++mt) {
                const int r = wm + mt * 16 + l16;
                af[mt] = *(const i32x4*)(sA + r * 128 + (((j * 4 + quad) ^ (r & 7)) * 16));
            }
#pragma unroll
            for (int nt = 0; nt < 4; ++nt) {
                const int n = wn + nt * 16 + l16;
                bfr[nt] = *(const i32x4*)(sB + n * 128 + (((j * 4 + quad) ^ (n & 7)) * 16));
            }
#pragma unroll
            for (int mt = 0; mt < 4; ++mt)
#pragma unroll
                for (int nt = 0; nt < 4; ++nt)
                    acc[mt][nt] = __builtin_amdgcn_mfma_i32_16x16x64_i8(
                        af[mt], bfr[nt], acc[mt][nt], 0, 0, 0);
        }
    }

    const float sc = (MODE == 2) ? (1.f / 32768.f) : (1.f / 16384.f);
#pragma unroll
    for (int mt = 0; mt < 4; ++mt) {
#pragma unroll
        for (int nt = 0; nt < 4; ++nt) {
            const int n = n0 + wn + nt * 16 + l16;
            const float bvf = bias[n];
#pragma unroll
            for (int i = 0; i < 4; ++i) {
                const int m = m0 + wm + quad * 4 + i + mt * 16;
                if (m >= M) continue;
                float v = (float)acc[mt][nt][i] * sc + bvf;
                if (MODE == 2) {
                    const size_t idx = (size_t)m * N + n;
                    ((float*)out)[idx] = extra[idx] + v;
                } else {  // MODE 3: quickgelu -> i8 x32
                    float g = v / (1.0f + __expf(-1.702f * v));
                    ((u8*)out)[(size_t)m * N + n] = (u8)q8(g, 32.f);
                }
            }
        }
    }
}

// ---------------- MFMA attention v5: K staged in LDS (union with sP) ----------------
// Round-2 PMC: 122us, MfmaUtil 4.6%, VALU 14.5%, HBM 5.6% -> latency/L2-bound.
// Root cause: QK^T read K as 16B/lane at 2KB row stride (25% sector eff., 64 sectors
// per wave-load, 20x redundant per head). Fix: stage K-head once per block into LDS
// via coalesced g2lds16 (8 lanes per 128B row), source-side XOR swizzle chunk^(row&7)
// (linear LDS dest, rule 21); QK reads chunk quad^(l16&7) -> 2 lanes/chunk = free.
// sK [272][64]u16 (34.8KB) ALIASES sP [64][296]u16 (37.9KB): K dead after QK^T,
// extra barrier before softmax overwrites -> LDS stays 38KB -> 4 blocks/CU.
// Keys >=257: staged rows clamped to 256 (real data); keys 272..287 read leftover
// LDS (in-bounds of union) -> masked by `valid` exactly as before (pv=0 stored).
#define ATT_PS 296
#define ATT_KROWS 272
__global__ __launch_bounds__(256, 4)
void attn_mfma_kernel(const u16* __restrict__ q, const u16* __restrict__ k,
                      const u16* __restrict__ vT, u16* __restrict__ o) {
    __shared__ __align__(16) u16 sU[64 * ATT_PS];   // 37888 B union: sK / sP
    __shared__ float sInv[64];
    u16* const sK = sU;    // [ATT_KROWS][64] u16, 16B chunks swizzled c^(row&7)
    u16* const sP = sU;    // [64][ATT_PS] u16

    const int t = threadIdx.x;
    const int wave = t >> 6, lane = t & 63;
    const int quad = lane >> 4, l16 = lane & 15;

    const int lid = blockIdx.x;
    const int g = lid / 40, local = lid - g * 40;
    const int qt = local >> 3, x = local & 7;
    const int hb = g * 8 + x;
    const int h = hb & (H_CNT - 1), b = hb >> 4;
    const int q0 = qt * 64;
    const size_t head = (size_t)b * N_SEQ * D_DIM + (size_t)h * HD_DIM;

    // ---- stage K head (rows 0..271, clamp >=257) into sK, swizzled source ----
    const u16* khead = k + head;
#pragma unroll
    for (int p = 0; p < 9; ++p) {
        const int c = p * 256 + t;           // 16B chunk id: row=c>>3, chunk=c&7
        if (c < ATT_KROWS * 8) {
            const int row = c >> 3;
            const int gr = row > N_SEQ - 1 ? N_SEQ - 1 : row;
            const int sg = (c & 7) ^ (row & 7);
            g2lds16(khead + (size_t)gr * D_DIM + sg * 8, sK + c * 8);
        }
    }

    int qrow = q0 + wave * 16 + l16; if (qrow > N_SEQ - 1) qrow = N_SEQ - 1;
    const u16* qp = q + head + (size_t)qrow * D_DIM + quad * 8;
    bf16x8 qf0 = *(const bf16x8*)(qp);
    bf16x8 qf1 = *(const bf16x8*)(qp + 32);

    asm volatile("s_waitcnt vmcnt(0)" ::: "memory");   // K staged (Q also drained)
    __syncthreads();

    // ---- QK^T from LDS (key&7 == l16&7 for all fragments -> hoisted chunks) ----
    const int xc0 = (quad ^ (l16 & 7)) * 8;
    const int xc1 = ((quad + 4) ^ (l16 & 7)) * 8;
    f32x4 s[5][4];
#pragma unroll
    for (int kt = 0; kt < 5; ++kt) {
        const int ntMax = (kt == 4) ? 2 : 4;
#pragma unroll
        for (int nt = 0; nt < 4; ++nt) {
            if (nt >= ntMax) continue;
            s[kt][nt] = {0.f, 0.f, 0.f, 0.f};
            const int key = kt * 64 + nt * 16 + l16;
            const u16* kr = sK + key * 64;
            bf16x8 b0 = *(const bf16x8*)(kr + xc0);
            bf16x8 b1 = *(const bf16x8*)(kr + xc1);
            s[kt][nt] = __builtin_amdgcn_mfma_f32_16x16x32_bf16(qf0, b0, s[kt][nt], 0, 0, 0);
            s[kt][nt] = __builtin_amdgcn_mfma_f32_16x16x32_bf16(qf1, b1, s[kt][nt], 0, 0, 0);
        }
    }
    __syncthreads();   // all waves done reading sK before sP overwrites it

#pragma unroll
    for (int i = 0; i < 4; ++i) {
        float mx = -1e30f;
#pragma unroll
        for (int kt = 0; kt < 5; ++kt) {
            const int ntMax = (kt == 4) ? 2 : 4;
#pragma unroll
            for (int nt = 0; nt < 4; ++nt) {
                if (nt >= ntMax) continue;
                const bool valid = (kt < 4) || (nt == 0 && l16 == 0);
                if (valid) mx = fmaxf(mx, s[kt][nt][i]);
            }
        }
        mx = fmaxf(mx, __shfl_xor(mx, 1, 64));
        mx = fmaxf(mx, __shfl_xor(mx, 2, 64));
        mx = fmaxf(mx, __shfl_xor(mx, 4, 64));
        mx = fmaxf(mx, __shfl_xor(mx, 8, 64));
        float sum = 0.f;
        const int prow = wave * 16 + quad * 4 + i;
#pragma unroll
        for (int kt = 0; kt < 5; ++kt) {
            const int ntMax = (kt == 4) ? 2 : 4;
#pragma unroll
            for (int nt = 0; nt < 4; ++nt) {
                if (nt >= ntMax) continue;
                const bool valid = (kt < 4) || (nt == 0 && l16 == 0);
                float pv = 0.f;
                if (valid) { pv = __expf(s[kt][nt][i] - mx); sum += pv; }
                sP[prow * ATT_PS + kt * 64 + nt * 16 + l16] = f2b(pv);
            }
        }
        sum += __shfl_xor(sum, 1, 64);
        sum += __shfl_xor(sum, 2, 64);
        sum += __shfl_xor(sum, 4, 64);
        sum += __shfl_xor(sum, 8, 64);
        if (l16 == 0) sInv[prow] = 1.0f / sum;
    }
    __syncthreads();   // orders u16 stores vs bf16-vector loads of sP

    f32x4 oacc[4] = {{0.f,0.f,0.f,0.f},{0.f,0.f,0.f,0.f},
                     {0.f,0.f,0.f,0.f},{0.f,0.f,0.f,0.f}};
    const u16* vhead = vT + ((size_t)b * D_DIM + h * HD_DIM) * VT_NP;
    const int prr = wave * 16 + l16;
#pragma unroll
    for (int kt = 0; kt < 5; ++kt) {
        const int j0 = kt * 64;
        bf16x8 p0 = *(const bf16x8*)(sP + prr * ATT_PS + j0 + quad * 8);
        bf16x8 p1;
        if (kt < 4) p1 = *(const bf16x8*)(sP + prr * ATT_PS + j0 + quad * 8 + 32);
#pragma unroll
        for (int nt = 0; nt < 4; ++nt) {
            const u16* vr = vhead + (size_t)(nt * 16 + l16) * VT_NP + j0 + quad * 8;
            bf16x8 b0 = *(const bf16x8*)(vr);
            oacc[nt] = __builtin_amdgcn_mfma_f32_16x16x32_bf16(p0, b0, oacc[nt], 0, 0, 0);
            if (kt < 4) {
                bf16x8 b1 = *(const bf16x8*)(vr + 32);
                oacc[nt] = __builtin_amdgcn_mfma_f32_16x16x32_bf16(p1, b1, oacc[nt], 0, 0, 0);
            }
        }
    }
#pragma unroll
    for (int nt = 0; nt < 4; ++nt) {
#pragma unroll
        for (int i = 0; i < 4; ++i) {
            const int mrow = wave * 16 + quad * 4 + i;
            const int m = q0 + mrow;
            if (m < N_SEQ) {
                o[head + (size_t)m * D_DIM + nt * 16 + l16] =
                    f2b(oacc[nt][i] * sInv[mrow]);
            }
        }
    }
}

extern "C" void kernel_launch(void* const* d_in, const int* in_sizes, int n_in,
                              void* d_out, int out_size, void* d_ws, size_t ws_size,
                              hipStream_t stream) {
    const float* hs   = (const float*)d_in[0];
    const float* ln1w = (const float*)d_in[1];
    const float* ln1b = (const float*)d_in[2];
    const float* wq   = (const float*)d_in[3];
    const float* bq   = (const float*)d_in[4];
    const float* wk   = (const float*)d_in[5];
    const float* bk   = (const float*)d_in[6];
    const float* wv   = (const float*)d_in[7];
    const float* bv   = (const float*)d_in[8];
    const float* wo   = (const float*)d_in[9];
    const float* bo   = (const float*)d_in[10];
    const float* ln2w = (const float*)d_in[11];
    const float* ln2b = (const float*)d_in[12];
    const float* w1   = (const float*)d_in[13];
    const float* b1   = (const float*)d_in[14];
    const float* w2   = (const float*)d_in[15];
    const float* b2   = (const float*)d_in[16];

    char* p = (char*)d_ws;
    size_t off = 0;
    auto alloc = [&](size_t bytes) {
        char* r = p + off;
        off += (bytes + 255) & ~(size_t)255;
        return (void*)r;
    };
    const int M = M_TOK;
    // bf16 weight block: contiguous (cvt_all writes linearly): wqkv | wo
    u16* wqkvb = (u16*)alloc((size_t)3 * D_DIM * D_DIM * 2);
    u16* wob   = (u16*)alloc((size_t)D_DIM * D_DIM * 2);
    u8*  w1i8  = (u8*) alloc((size_t)FF_DIM * D_DIM);
    u8*  w2i8  = (u8*) alloc((size_t)D_DIM * FF_DIM);
    float* bqkv = (float*)alloc((size_t)3 * D_DIM * 4);
    u16*  x_ln = (u16*) alloc((size_t)M * D_DIM * 2);
    u16*  qb   = (u16*) alloc((size_t)M * D_DIM * 2);
    u16*  kb   = (u16*) alloc((size_t)M * D_DIM * 2);
    u16*  vTb  = (u16*) alloc((size_t)B_SZ * D_DIM * VT_NP * 2);
    u16*  ab   = (u16*) alloc((size_t)M * D_DIM * 2);
    float* hid = (float*)alloc((size_t)M * D_DIM * 4);
    // i8 aliases (regions dead after o-proj): h1i8 over qb+kb (42 MB), x2i8 over ab
    u8* h1i8 = (u8*)qb;
    u8* x2i8 = (u8*)ab;

    const int nDD = D_DIM * D_DIM, nFD = FF_DIM * D_DIM;
    const int WB8 = (4 * nDD) / 8, WF8 = (2 * nFD) / 8;
    cvt_all_kernel<<<(WB8 + WF8 + 3 * D_DIM + 255) / 256, 256, 0, stream>>>(
        wq, wk, wv, wo, w1, w2, bq, bk, bv, wqkvb, w1i8, w2i8, bqkv);

    ln_kernel<false><<<M, 256, 0, stream>>>(hs, ln1w, ln1b, x_ln);

    const int gM256 = (M + 255) / 256;            // 41
    gemm256_kernel<5><<<gM256 * (3 * D_DIM / 256), 512, 0, stream>>>(
        x_ln, wqkvb, bqkv, nullptr, qb, kb, vTb, M, 3 * D_DIM, D_DIM);

    attn_mfma_kernel<<<5 * H_CNT * B_SZ, 256, 0, stream>>>(qb, kb, vTb, ab);

    gemm256_kernel<2><<<gM256 * (D_DIM / 256), 512, 0, stream>>>(
        ab, wob, bo, hs, hid, nullptr, nullptr, M, D_DIM, D_DIM);

    ln_kernel<true><<<M, 256, 0, stream>>>(hid, ln2w, ln2b, x2i8);

    const int gM = (M + 127) / 128;  // 81
    dim3 gF(gM, FF_DIM / 128);       // 81 x 32
    gemm_i8_kernel<3><<<gF, 256, 0, stream>>>(x2i8, w1i8, b1, nullptr, h1i8,
                                              M, FF_DIM, D_DIM, 16);
    dim3 gD(gM, D_DIM / 128);        // 81 x 8
    gemm_i8_kernel<2><<<gD, 256, 0, stream>>>(h1i8, w2i8, b2, hid, (float*)d_out,
                                              M, D_DIM, FF_DIM, 4);
}